// Round 4
// baseline (426.560 us; speedup 1.0000x reference)
//
#include <hip/hip_runtime.h>
#include <cstdint>
#include <cstddef>

typedef __bf16 bf16x8 __attribute__((ext_vector_type(8)));
typedef float f32x4 __attribute__((ext_vector_type(4)));
typedef float f32x2 __attribute__((ext_vector_type(2)));

__device__ __forceinline__ float bf2f(unsigned short u){
  unsigned int x = ((unsigned int)u) << 16;
  return __builtin_bit_cast(float, x);
}
__device__ __forceinline__ unsigned short f2bf(float f){
  unsigned int x = __builtin_bit_cast(unsigned int, f);
  x += 0x7fffu + ((x >> 16) & 1u);
  return (unsigned short)(x >> 16);
}
__device__ __forceinline__ f32x2 splat2(float s){ return (f32x2){s, s}; }

// ---- cross-lane reductions on the (idle) LDS pipe: ds_swizzle butterflies ----
template<int P> __device__ __forceinline__ float swz_add(float x){
  int y = __builtin_amdgcn_ds_swizzle(__builtin_bit_cast(int, x), P);
  return x + __builtin_bit_cast(float, y);
}
__device__ __forceinline__ float sum16(float x){
  x = swz_add<0x041F>(x);   // xor 1  (BitMode: and=0x1F, or=0, xor=k)
  x = swz_add<0x081F>(x);   // xor 2
  x = swz_add<0x101F>(x);   // xor 4
  x = swz_add<0x201F>(x);   // xor 8
  return x;
}
__device__ __forceinline__ float sum64(float x, int bpa){
  x = swz_add<0x041F>(x);
  x = swz_add<0x081F>(x);
  x = swz_add<0x101F>(x);
  x = swz_add<0x201F>(x);
  x = swz_add<0x401F>(x);   // xor 16 (within 32-lane group)
  int y = __builtin_amdgcn_ds_bpermute(bpa, __builtin_bit_cast(int, x)); // lane^32
  return x + __builtin_bit_cast(float, y);
}

__device__ __forceinline__ float load_w(const void* ew, int e, int f){
  return f ? ((const float*)ew)[e] : bf2f(((const unsigned short*)ew)[e]);
}

// fixed-point packing for the single 64b atomic:
//   acc[d] += (1<<40) | round(w * 2^24)
// high 24 bits = degree count (old>>40 == rank), low 40 bits = wsum in 2^-24.
#define WSUM_MASK  ((1ull << 40) - 1ull)
#define WSUM_SCALE 16777216.0f
#define WSUM_INV   (1.0f / 16777216.0f)

// ---------------- mega canon kernel ----------------

struct MegaArgs {
  const void* psrc[15]; float* pdst[15]; int pn[15]; float pscale[15];
  const void* wsrc[6]; unsigned short* wdst[6]; int wM[6];
  const void* x; unsigned short* xc; int n4;
  int* cnt; int nz4;
  int* flag;
};

__global__ __launch_bounds__(256) void k_mega(MegaArgs a){
  __shared__ int sf;
  if (threadIdx.x == 0) sf = 0;
  __syncthreads();
  {
    unsigned short u = ((const unsigned short*)a.x)[threadIdx.x];
    int expo = (u >> 7) & 0xFF;
    if (expo >= 0xC0) atomicOr(&sf, 1);
  }
  __syncthreads();
  int f = sf;
  int b = blockIdx.x;

  if (b == 0){
    if (threadIdx.x == 0) a.flag[0] = f;
    for (int t = 0; t < 15; t++){
      int i = threadIdx.x;
      if (i < a.pn[t]){
        float v = f ? ((const float*)a.psrc[t])[i]
                    : bf2f(((const unsigned short*)a.psrc[t])[i]);
        a.pdst[t][i] = v * a.pscale[t];
      }
    }
    return;
  }
  b -= 1;
  if (b < 320){
    int t, base;
    if      (b <  64){ t = 0; base = b;       }
    else if (b < 128){ t = 1; base = b - 64;  }
    else if (b < 192){ t = 2; base = b - 128; }
    else if (b < 256){ t = 3; base = b - 192; }
    else if (b < 288){ t = 4; base = b - 256; }
    else             { t = 5; base = b - 288; }
    int M = a.wM[t];
    int idx = base*256 + threadIdx.x;
    if (idx < 128*M){
      int k = idx / M, m2 = idx % M;
      unsigned short v = f ? f2bf(((const float*)a.wsrc[t])[idx])
                           : ((const unsigned short*)a.wsrc[t])[idx];
      a.wdst[t][m2*128 + k] = v;
    }
    return;
  }
  b -= 320;
  int xB = (a.n4 + 255) / 256;
  if (b < xB){
    int i = b*256 + threadIdx.x;
    if (i < a.n4){
      if (f){
        float4 v = ((const float4*)a.x)[i];
        ushort4 o;
        o.x = f2bf(v.x); o.y = f2bf(v.y); o.z = f2bf(v.z); o.w = f2bf(v.w);
        ((ushort4*)a.xc)[i] = o;
      } else {
        ((ushort4*)a.xc)[i] = ((const ushort4*)a.x)[i];
      }
    }
    return;
  }
  b -= xB;
  int i = b*256 + threadIdx.x;
  if (i < a.nz4) ((int4*)a.cnt)[i] = make_int4(0, 0, 0, 0);
}

// ---------------- graph build ----------------

// ONE packed u64 atomic per edge: degree count + fixed-point weight sum,
// returned old value's high bits give rank (stable slot within dst segment).
__global__ void k_hist(const int* __restrict__ ei, const void* __restrict__ ew,
                       unsigned long long* __restrict__ acc,
                       int* __restrict__ rank, int E, int n,
                       const int* __restrict__ flag){
  int e = blockIdx.x*256 + threadIdx.x;
  if (e < E){
    int d = ei[E + e];
    int r = 0;
    if ((unsigned)d < (unsigned)n){
      float w = load_w(ew, e, flag[0]);
      unsigned int wq = (unsigned int)(w * WSUM_SCALE + 0.5f);
      unsigned long long pk = (1ull << 40) | (unsigned long long)wq;
      unsigned long long old = atomicAdd(&acc[d], pk);
      r = (int)(old >> 40);
    }
    rank[e] = r;
  }
}

__global__ void k_scan1(const unsigned long long* __restrict__ acc,
                        int* __restrict__ bsum, int n){
  int i = blockIdx.x*256 + threadIdx.x;
  int lane = threadIdx.x & 63, w = threadIdx.x >> 6;
  int v = (i < n) ? (int)(acc[i] >> 40) + 1 : 0;
  for (int off = 32; off; off >>= 1) v += __shfl_down(v, off);
  __shared__ int ws[4];
  if (lane == 0) ws[w] = v;
  __syncthreads();
  if (threadIdx.x == 0) bsum[blockIdx.x] = ws[0] + ws[1] + ws[2] + ws[3];
}

// fused scan phases 2+3
__global__ void k_scan3(const unsigned long long* __restrict__ acc,
                        const int* __restrict__ bsum,
                        int* __restrict__ rowptr, int n, int nB){
  int b = blockIdx.x, tid = threadIdx.x;
  int lane = tid & 63, w = tid >> 6;
  __shared__ int ws[4];
  __shared__ int sboff;

  int part = 0;
  for (int t = tid; t < b; t += 256) part += bsum[t];
  for (int off = 32; off; off >>= 1) part += __shfl_down(part, off);
  if (lane == 0) ws[w] = part;
  __syncthreads();
  if (tid == 0) sboff = ws[0] + ws[1] + ws[2] + ws[3];
  __syncthreads();
  int boff = sboff;
  __syncthreads();

  int i = b*256 + tid;
  int v = (i < n) ? (int)(acc[i] >> 40) + 1 : 0;
  int sv = v;
  for (int off = 1; off < 64; off <<= 1){
    int t = __shfl_up(sv, off);
    if (lane >= off) sv += t;
  }
  if (lane == 63) ws[w] = sv;
  __syncthreads();
  if (tid == 0){
    int acc2 = 0;
    for (int k = 0; k < 4; k++){ int t = ws[k]; ws[k] = acc2; acc2 += t; }
  }
  __syncthreads();
  if (i < n) rowptr[i + 1] = boff + ws[w] + sv;
  if (i == 0) rowptr[0] = 0;
  (void)nB;
}

// fused: ATOMIC-FREE scatter (blocks [0,Eb)) + self-loop write (blocks [Eb,..)).
__global__ void k_scat_self(const int* __restrict__ ei, const void* __restrict__ ew,
                            const int* __restrict__ rank, const int* __restrict__ rowptr,
                            const unsigned long long* __restrict__ acc,
                            uint2* __restrict__ csr,
                            int E, int n, int ET, const int* __restrict__ flag, int Eb){
  int b = blockIdx.x;
  if (b < Eb){
    int e = b*256 + threadIdx.x;
    if (e < E){
      int s = ei[e], d = ei[E + e];
      if ((unsigned)d < (unsigned)n){
        int pos = rowptr[d] + rank[e];
        if ((unsigned)pos < (unsigned)ET){
          float w = load_w(ew, e, flag[0]);
          csr[pos] = make_uint2((unsigned)s, __builtin_bit_cast(unsigned, w));
        }
      }
    }
  } else {
    int i = (b - Eb)*256 + threadIdx.x;
    if (i < n){
      int beg = rowptr[i], endv = rowptr[i+1];
      int deg = endv - 1 - beg;
      float ws = (float)(acc[i] & WSUM_MASK) * WSUM_INV;
      float w = ws / fmaxf((float)deg, 1.0f);
      csr[endv - 1] = make_uint2((unsigned)i, __builtin_bit_cast(unsigned, w));
    }
  }
}

// ---------------- GEMM: xl (bf16 out) and xr (f32 out) in one launch ----------------

template<int NC>
__global__ __launch_bounds__(64) void k_gemm2(
  const unsigned short* __restrict__ A,
  const unsigned short* __restrict__ WTl, const unsigned short* __restrict__ WTr,
  const float* __restrict__ bl, const float* __restrict__ br,
  unsigned short* __restrict__ outL, float* __restrict__ outR,
  int nrows)
{
  constexpr int CT = NC / 16;
  int lane = threadIdx.x;
  int q = lane >> 4, rr = lane & 15;
  int r0 = blockIdx.x * 16;
  bool isR = blockIdx.y == 1;
  const unsigned short* WT = isR ? WTr : WTl;
  const float* bia         = isR ? br  : bl;

  f32x4 acc[CT];
  #pragma unroll
  for (int b = 0; b < CT; b++) acc[b] = (f32x4){0.f, 0.f, 0.f, 0.f};

  int row = r0 + rr;
  if (row >= nrows) row = nrows - 1;

  #pragma unroll
  for (int kc = 0; kc < 4; kc++){
    bf16x8 af = *(const bf16x8*)(A + (size_t)row*128 + kc*32 + q*8);
    #pragma unroll
    for (int ct = 0; ct < CT; ct++){
      bf16x8 bfr = *(const bf16x8*)(WT + (size_t)(ct*16 + rr)*128 + kc*32 + q*8);
      acc[ct] = __builtin_amdgcn_mfma_f32_16x16x32_bf16(af, bfr, acc[ct], 0, 0, 0);
    }
  }

  // C/D layout: col = lane&15, row = (lane>>4)*4 + reg
  #pragma unroll
  for (int ct = 0; ct < CT; ct++){
    int col = ct*16 + rr;
    float bv = bia[col];
    #pragma unroll
    for (int t = 0; t < 4; t++){
      int orow = r0 + q*4 + t;
      if (orow < nrows){
        float v = acc[ct][t] + bv;
        if (isR) outR[(size_t)orow*NC + col] = v;
        else     outL[(size_t)orow*NC + col] = f2bf(v);
      }
    }
  }
}

// ---------------- fused edge scoring + online-softmax aggregation ----------------
// Round-4: packed-f32 (VOP3P v_pk_*_f32) channel math — each lane owns 2
// channels, all per-edge FMAs done 2-wide; serial remainder loop replaced by
// one masked SIMD block (pp[j] = -1e30 for j >= rem -> exp2 = 0 contribution).

__global__ __launch_bounds__(256) void k_edge128(
  const unsigned short* __restrict__ xl, const float* __restrict__ xr,
  const int* __restrict__ rowptr, const uint2* __restrict__ csr,
  const float* __restrict__ We, const float* __restrict__ att,
  const float* __restrict__ bias, unsigned short* __restrict__ out, int n, int ET)
{
  int wid = threadIdx.x >> 6;
  int lane = threadIdx.x & 63;
  int node = __builtin_amdgcn_readfirstlane(blockIdx.x*4 + wid);
  if (node >= n) return;
  int ch = lane*2;
  f32x2 wev  = *(const f32x2*)(We + ch);
  f32x2 attv = *(const f32x2*)(att + ch);    // pre-scaled by log2e
  f32x2 fxrv = *(const f32x2*)(xr + (size_t)node*128 + ch);
  int beg = rowptr[node], end = rowptr[node+1];
  if (beg < 0) beg = 0;
  if (end > ET) end = ET;

  float m = -1e30f, l = 0.f;
  f32x2 av = (f32x2){0.f, 0.f};

  int sc_[8]; float wc_[8];
  int sn_[8]; float wn_[8];

  auto loadblk = [&](int base, int* S, float* W){
    #pragma unroll
    for (int j = 0; j < 8; j++){
      uint2 pk = csr[base + j];          // uniform addr -> s_load
      int sv = (int)pk.x;
      if ((unsigned)sv >= (unsigned)n) sv = 0;
      S[j] = sv;
      W[j] = __builtin_bit_cast(float, pk.y);
    }
  };
  auto loadblkm = [&](int base, int* S, float* W){
    #pragma unroll
    for (int j = 0; j < 8; j++){
      int idx = base + j; if (idx > end - 1) idx = end - 1;   // clamp (scalar)
      uint2 pk = csr[idx];
      int sv = (int)pk.x;
      if ((unsigned)sv >= (unsigned)n) sv = 0;
      S[j] = sv;
      W[j] = __builtin_bit_cast(float, pk.y);
    }
  };

  int deg = end - beg;
  int nbf = deg >> 3;          // full blocks
  int rem = deg & 7;

  // one block's worth of work; c = valid count (8 for full blocks)
  auto doblk = [&](const int* S, const float* W, int c){
    unsigned u[8];
    #pragma unroll
    for (int j = 0; j < 8; j++){
      const unsigned short* rp = xl + (size_t)S[j]*128;   // scalar base
      u[j] = *(const unsigned int*)(rp + ch);             // saddr + v_ch
    }
    return [&, c](f32x2* xv, float* pp, const unsigned* uu){ (void)xv; (void)pp; (void)uu; };
  };
  (void)doblk;

  auto process = [&](const int* S, const float* W, const unsigned* u, int c){
    f32x2 xv[8]; float pp[8];
    #pragma unroll
    for (int j = 0; j < 8; j++){
      f32x2 x2;
      x2.x = __builtin_bit_cast(float, u[j] << 16);
      x2.y = __builtin_bit_cast(float, u[j] & 0xffff0000u);
      xv[j] = x2;
      f32x2 t  = __builtin_elementwise_fma(splat2(W[j]), wev, fxrv) + x2;  // pk_fma + pk_add
      f32x2 lr = __builtin_elementwise_max(t, 0.2f*t);                     // pk_mul + pk_max
      f32x2 pr = lr * attv;                                                // pk_mul
      float p  = sum16(pr.x + pr.y);
      pp[j] = (j < c) ? p : -1e30f;
    }
    float mx = fmaxf(fmaxf(fmaxf(pp[0], pp[1]), fmaxf(pp[2], pp[3])),
                     fmaxf(fmaxf(pp[4], pp[5]), fmaxf(pp[6], pp[7])));
    float nm = fmaxf(m, mx);
    float sc = exp2f(m - nm);
    float el = 0.f;
    f32x2 ev = (f32x2){0.f, 0.f};
    #pragma unroll
    for (int j = 0; j < 8; j++){
      float e = exp2f(pp[j] - nm);
      el += e;
      ev = __builtin_elementwise_fma(splat2(e), xv[j], ev);                // pk_fma
    }
    l  = l*sc + el;
    av = __builtin_elementwise_fma(splat2(sc), av, ev);                    // pk_fma
    m  = nm;
  };

  if (nbf > 0){
    loadblk(beg, sc_, wc_);
    for (int b = 0; b < nbf; b++){
      unsigned u[8];
      #pragma unroll
      for (int j = 0; j < 8; j++){
        const unsigned short* rp = xl + (size_t)sc_[j]*128;
        u[j] = *(const unsigned int*)(rp + ch);
      }
      int nbase = beg + (b + 1)*8;
      if (b + 1 < nbf)      loadblk (nbase, sn_, wn_);
      else if (rem)         loadblkm(nbase, sn_, wn_);
      process(sc_, wc_, u, 8);
      #pragma unroll
      for (int j = 0; j < 8; j++){ sc_[j] = sn_[j]; wc_[j] = wn_[j]; }
    }
  } else if (rem){
    loadblkm(beg, sc_, wc_);
  }
  if (rem){
    unsigned u[8];
    #pragma unroll
    for (int j = 0; j < 8; j++){
      const unsigned short* rp = xl + (size_t)sc_[j]*128;
      u[j] = *(const unsigned int*)(rp + ch);
    }
    process(sc_, wc_, u, rem);
  }

  float inv = 1.0f / (l + 1e-16f);
  f32x2 biasv = *(const f32x2*)(bias + ch);
  f32x2 o = __builtin_elementwise_fma(splat2(inv), av, biasv);
  float o0 = o.x, o1 = o.y;
  o0 = o0 > 0.f ? o0 : (__expf(o0) - 1.0f);   // ELU (layers 0,1)
  o1 = o1 > 0.f ? o1 : (__expf(o1) - 1.0f);
  unsigned int packed = (unsigned int)f2bf(o0) | ((unsigned int)f2bf(o1) << 16);
  *(unsigned int*)(out + (size_t)node*128 + ch) = packed;
}

__global__ __launch_bounds__(256) void k_edge64(
  const unsigned short* __restrict__ xl, const float* __restrict__ xr,
  const int* __restrict__ rowptr, const uint2* __restrict__ csr,
  const float* __restrict__ We, const float* __restrict__ att,
  const float* __restrict__ bias, void* __restrict__ out, int n, int ET,
  const int* __restrict__ flag)
{
  int wid = threadIdx.x >> 6;
  int lane = threadIdx.x & 63;
  int node = __builtin_amdgcn_readfirstlane(blockIdx.x*4 + wid);
  if (node >= n) return;
  float we0 = We[lane];
  float at0 = att[lane];          // pre-scaled by log2e
  float c1 = 0.6f*at0, c2 = 0.4f*at0;
  float fxr0 = xr[(size_t)node*64 + lane];
  int bpa = ((lane ^ 32) << 2);
  int beg = rowptr[node], end = rowptr[node+1];
  if (beg < 0) beg = 0;
  if (end > ET) end = ET;
  float m = -1e30f, l = 0.f, a0 = 0.f;

  auto loadblk = [&](int base, int* S, float* W){
    #pragma unroll
    for (int j = 0; j < 8; j++){
      uint2 pk = csr[base + j];
      int sv = (int)pk.x;
      if ((unsigned)sv >= (unsigned)n) sv = 0;
      S[j] = sv;
      W[j] = __builtin_bit_cast(float, pk.y);
    }
  };

  int i = beg;
  int sc_[8]; float wc_[8];
  bool have = (i + 8 <= end);
  if (have) loadblk(i, sc_, wc_);
  while (have){
    float x[8];
    #pragma unroll
    for (int j = 0; j < 8; j++){
      const unsigned short* rp = xl + (size_t)sc_[j]*64;
      x[j] = bf2f(rp[lane]);
    }
    bool hnext = (i + 16 <= end);
    int sn_[8]; float wn_[8];
    if (hnext) loadblk(i + 8, sn_, wn_);

    float pp[8];
    #pragma unroll
    for (int j = 0; j < 8; j++){
      float t = fmaf(wc_[j], we0, fxr0) + x[j];
      float p = fmaf(c1, t, c2*fabsf(t));
      pp[j] = sum64(p, bpa);
    }
    float mx = fmaxf(fmaxf(fmaxf(pp[0], pp[1]), fmaxf(pp[2], pp[3])),
                     fmaxf(fmaxf(pp[4], pp[5]), fmaxf(pp[6], pp[7])));
    float nm = fmaxf(m, mx);
    float sc = exp2f(m - nm);
    float el = 0.f, ea = 0.f;
    #pragma unroll
    for (int j = 0; j < 8; j++){
      float e = exp2f(pp[j] - nm);
      el += e;
      ea += e*x[j];
    }
    l  = l*sc  + el;
    a0 = a0*sc + ea;
    m = nm;
    i += 8;
    have = hnext;
    if (have){
      #pragma unroll
      for (int j = 0; j < 8; j++){ sc_[j] = sn_[j]; wc_[j] = wn_[j]; }
    }
  }
  for (; i < end; i++){
    uint2 pk = csr[i];
    int sv = (int)pk.x;
    if ((unsigned)sv >= (unsigned)n) sv = 0;
    float w = __builtin_bit_cast(float, pk.y);
    float x0 = bf2f(xl[(size_t)sv*64 + lane]);
    float t0 = fmaf(w, we0, fxr0) + x0;
    float p  = fmaf(c1, t0, c2*fabsf(t0));
    p = sum64(p, bpa);
    float nm = fmaxf(m, p);
    float scv = exp2f(m - nm);
    float pe  = exp2f(p - nm);
    l  = l*scv  + pe;
    a0 = a0*scv + pe*x0;
    m = nm;
  }
  float inv = 1.0f / (l + 1e-16f);
  float res = a0*inv + bias[lane];
  size_t oi = (size_t)node*64 + lane;
  if (flag[0]) ((float*)out)[oi] = res;
  else         ((unsigned short*)out)[oi] = f2bf(res);
}

// ---------------- host ----------------

extern "C" void kernel_launch(void* const* d_in, const int* in_sizes, int n_in,
                              void* d_out, int out_size, void* d_ws, size_t ws_size,
                              hipStream_t stream)
{
  (void)n_in; (void)out_size; (void)ws_size;
  const void* x   = d_in[0];
  const int*  ei  = (const int*)d_in[1];
  const void* ew  = d_in[2];

  const int N = in_sizes[0] / 128;
  const int E = in_sizes[2];
  const int ET = E + N;
  const int nB = (N + 255) / 256;

  char* p = (char*)d_ws;
  size_t off = 0;
  auto carve = [&](size_t bytes)->void* {
    void* r = p + off;
    off = (off + bytes + 255) & ~(size_t)255;
    return r;
  };
  const int accG = (N + 1) / 2;                 // int4 granules for acc zeroing
  int*                flag   = (int*)carve(4);
  unsigned long long* acc    = (unsigned long long*)carve((size_t)accG*16);
  int*                rowptr = (int*)carve((size_t)(N+1)*4);
  int*                bsum   = (int*)carve((size_t)nB*4);
  int*                rank   = (int*)carve((size_t)E*4);
  uint2*              csr    = (uint2*)carve((size_t)ET*8);
  float*              prm    = (float*)carve(15*128*4);
  unsigned short*     WT0l   = (unsigned short*)carve(128*128*2);
  unsigned short*     WT0r   = (unsigned short*)carve(128*128*2);
  unsigned short*     WT1l   = (unsigned short*)carve(128*128*2);
  unsigned short*     WT1r   = (unsigned short*)carve(128*128*2);
  unsigned short*     WT2l   = (unsigned short*)carve(128*64*2);
  unsigned short*     WT2r   = (unsigned short*)carve(128*64*2);
  unsigned short*     xc     = (unsigned short*)carve((size_t)N*128*2);
  unsigned short*     xlb16  = (unsigned short*)carve((size_t)N*128*2);
  float*              xrb    = (float*)carve((size_t)N*128*4);
  unsigned short*     hb     = (unsigned short*)carve((size_t)N*128*2);

  float* bl0c = prm + 0*128;  float* br0c = prm + 1*128;
  float* We0c = prm + 2*128;  float* at0c = prm + 3*128;  float* bi0c = prm + 4*128;
  float* bl1c = prm + 5*128;  float* br1c = prm + 6*128;
  float* We1c = prm + 7*128;  float* at1c = prm + 8*128;  float* bi1c = prm + 9*128;
  float* bl2c = prm + 10*128; float* br2c = prm + 11*128;
  float* We2c = prm + 12*128; float* at2c = prm + 13*128; float* bi2c = prm + 14*128;

  const float LOG2E = 1.4426950408889634f;
  MegaArgs ma;
  {
    const void* srcs[15] = { d_in[4], d_in[6], d_in[7], d_in[8], d_in[9],
                             d_in[11], d_in[13], d_in[14], d_in[15], d_in[16],
                             d_in[18], d_in[20], d_in[21], d_in[22], d_in[23] };
    float* dsts[15] = { bl0c, br0c, We0c, at0c, bi0c,
                        bl1c, br1c, We1c, at1c, bi1c,
                        bl2c, br2c, We2c, at2c, bi2c };
    int ns[15] = {128,128,128,128,128, 128,128,128,128,128, 64,64,64,64,64};
    for (int i = 0; i < 15; i++){
      ma.psrc[i] = srcs[i]; ma.pdst[i] = dsts[i]; ma.pn[i] = ns[i];
      ma.pscale[i] = (i == 3 || i == 8 || i == 13) ? LOG2E : 1.0f;  // att slots
    }
    const void* wsrcs[6] = { d_in[3], d_in[5], d_in[10], d_in[12], d_in[17], d_in[19] };
    unsigned short* wdsts[6] = { WT0l, WT0r, WT1l, WT1r, WT2l, WT2r };
    int Ms[6] = {128, 128, 128, 128, 64, 64};
    for (int i = 0; i < 6; i++){ ma.wsrc[i] = wsrcs[i]; ma.wdst[i] = wdsts[i]; ma.wM[i] = Ms[i]; }
    ma.x = x; ma.xc = xc; ma.n4 = N*32;
    ma.cnt = (int*)acc; ma.nz4 = accG;
    ma.flag = flag;
  }
  int xB = (ma.n4 + 255) / 256;
  int zB = (ma.nz4 + 255) / 256;
  k_mega<<<1 + 320 + xB + zB, 256, 0, stream>>>(ma);

  // graph build: ONE u64 atomic/edge (hist+rank+wsum), 2-launch scan,
  // fused atomic-free scatter + self-loop write
  const int Eb = (E + 255) / 256;
  k_hist <<<Eb, 256, 0, stream>>>(ei, ew, acc, rank, E, N, flag);
  k_scan1<<<nB, 256, 0, stream>>>(acc, bsum, N);
  k_scan3<<<nB, 256, 0, stream>>>(acc, bsum, rowptr, N, nB);
  k_scat_self<<<Eb + nB, 256, 0, stream>>>(ei, ew, rank, rowptr, acc, csr, E, N, ET, flag, Eb);

  const int rowBlocks = (N + 15) / 16;

  // layer 0
  k_gemm2<128><<<dim3(rowBlocks, 2), 64, 0, stream>>>(xc, WT0l, WT0r, bl0c, br0c, xlb16, xrb, N);
  k_edge128<<<(N+3)/4, 256, 0, stream>>>(xlb16, xrb, rowptr, csr, We0c, at0c, bi0c, hb, N, ET);

  // layer 1
  k_gemm2<128><<<dim3(rowBlocks, 2), 64, 0, stream>>>(hb, WT1l, WT1r, bl1c, br1c, xlb16, xrb, N);
  k_edge128<<<(N+3)/4, 256, 0, stream>>>(xlb16, xrb, rowptr, csr, We1c, at1c, bi1c, hb, N, ET);

  // layer 2
  k_gemm2<64><<<dim3(rowBlocks, 2), 64, 0, stream>>>(hb, WT2l, WT2r, bl2c, br2c, xlb16, xrb, N);
  k_edge64<<<(N+3)/4, 256, 0, stream>>>(xlb16, xrb, rowptr, csr, We2c, at2c, bi2c,
                                        d_out, N, ET, flag);
}

// Round 5
// 416.191 us; speedup vs baseline: 1.0249x; 1.0249x over previous
//
#include <hip/hip_runtime.h>
#include <cstdint>
#include <cstddef>

typedef __bf16 bf16x8 __attribute__((ext_vector_type(8)));
typedef float f32x4 __attribute__((ext_vector_type(4)));

__device__ __forceinline__ float bf2f(unsigned short u){
  unsigned int x = ((unsigned int)u) << 16;
  return __builtin_bit_cast(float, x);
}
__device__ __forceinline__ unsigned short f2bf(float f){
  unsigned int x = __builtin_bit_cast(unsigned int, f);
  x += 0x7fffu + ((x >> 16) & 1u);
  return (unsigned short)(x >> 16);
}

// ---- cross-lane reductions on the (idle) LDS pipe: ds_swizzle butterflies ----
template<int P> __device__ __forceinline__ float swz_add(float x){
  int y = __builtin_amdgcn_ds_swizzle(__builtin_bit_cast(int, x), P);
  return x + __builtin_bit_cast(float, y);
}
__device__ __forceinline__ float sum16(float x){
  x = swz_add<0x041F>(x);   // xor 1  (BitMode: and=0x1F, or=0, xor=k)
  x = swz_add<0x081F>(x);   // xor 2
  x = swz_add<0x101F>(x);   // xor 4
  x = swz_add<0x201F>(x);   // xor 8
  return x;
}
__device__ __forceinline__ float sum64(float x, int bpa){
  x = swz_add<0x041F>(x);
  x = swz_add<0x081F>(x);
  x = swz_add<0x101F>(x);
  x = swz_add<0x201F>(x);
  x = swz_add<0x401F>(x);   // xor 16 (within 32-lane group)
  int y = __builtin_amdgcn_ds_bpermute(bpa, __builtin_bit_cast(int, x)); // lane^32
  return x + __builtin_bit_cast(float, y);
}

__device__ __forceinline__ float load_w(const void* ew, int e, int f){
  return f ? ((const float*)ew)[e] : bf2f(((const unsigned short*)ew)[e]);
}

// fixed-point packing for the single 64b atomic:
//   acc[d*ACCS] += (1<<40) | round(w * 2^24)
// high 24 bits = degree count (old>>40 == rank), low 40 bits = wsum in 2^-24.
// ACCS=16: one node per 128B line -> no false sharing at the L2 atomic unit.
#define WSUM_MASK  ((1ull << 40) - 1ull)
#define WSUM_SCALE 16777216.0f
#define WSUM_INV   (1.0f / 16777216.0f)
#define ACCS 16

// ---------------- mega canon kernel ----------------
// One launch: per-block dtype flag (256-short probe of x), param canon,
// weight transpose canon, x->bf16 canon, acc zeroing. Block ranges:
//   [0]                 params + flag store
//   [1, 321)            weight tensors (64,64,64,64,32,32 blocks)
//   [321, 321+xB)       x canon (ushort4 granules)
//   [321+xB, ...)       acc zero (int4 granules)

struct MegaArgs {
  const void* psrc[15]; float* pdst[15]; int pn[15]; float pscale[15];
  const void* wsrc[6]; unsigned short* wdst[6]; int wM[6];
  const void* x; unsigned short* xc; int n4;
  int* cnt; int nz4;
  int* flag;
};

__global__ __launch_bounds__(256) void k_mega(MegaArgs a){
  __shared__ int sf;
  if (threadIdx.x == 0) sf = 0;
  __syncthreads();
  {
    unsigned short u = ((const unsigned short*)a.x)[threadIdx.x];
    int expo = (u >> 7) & 0xFF;
    if (expo >= 0xC0) atomicOr(&sf, 1);
  }
  __syncthreads();
  int f = sf;
  int b = blockIdx.x;

  if (b == 0){
    if (threadIdx.x == 0) a.flag[0] = f;
    for (int t = 0; t < 15; t++){
      int i = threadIdx.x;
      if (i < a.pn[t]){
        float v = f ? ((const float*)a.psrc[t])[i]
                    : bf2f(((const unsigned short*)a.psrc[t])[i]);
        a.pdst[t][i] = v * a.pscale[t];
      }
    }
    return;
  }
  b -= 1;
  if (b < 320){
    int t, base;
    if      (b <  64){ t = 0; base = b;       }
    else if (b < 128){ t = 1; base = b - 64;  }
    else if (b < 192){ t = 2; base = b - 128; }
    else if (b < 256){ t = 3; base = b - 192; }
    else if (b < 288){ t = 4; base = b - 256; }
    else             { t = 5; base = b - 288; }
    int M = a.wM[t];
    int idx = base*256 + threadIdx.x;
    if (idx < 128*M){
      int k = idx / M, m2 = idx % M;
      unsigned short v = f ? f2bf(((const float*)a.wsrc[t])[idx])
                           : ((const unsigned short*)a.wsrc[t])[idx];
      a.wdst[t][m2*128 + k] = v;
    }
    return;
  }
  b -= 320;
  int xB = (a.n4 + 255) / 256;
  if (b < xB){
    int i = b*256 + threadIdx.x;
    if (i < a.n4){
      if (f){
        float4 v = ((const float4*)a.x)[i];
        ushort4 o;
        o.x = f2bf(v.x); o.y = f2bf(v.y); o.z = f2bf(v.z); o.w = f2bf(v.w);
        ((ushort4*)a.xc)[i] = o;
      } else {
        ((ushort4*)a.xc)[i] = ((const ushort4*)a.x)[i];
      }
    }
    return;
  }
  b -= xB;
  int i = b*256 + threadIdx.x;
  if (i < a.nz4) ((int4*)a.cnt)[i] = make_int4(0, 0, 0, 0);
}

// ---------------- graph build ----------------

// ONE packed u64 atomic per edge: degree count + fixed-point weight sum,
// returned old value's high bits give rank (stable slot within dst segment).
__global__ void k_hist(const int* __restrict__ ei, const void* __restrict__ ew,
                       unsigned long long* __restrict__ acc,
                       int* __restrict__ rank, int E, int n,
                       const int* __restrict__ flag){
  int e = blockIdx.x*256 + threadIdx.x;
  if (e < E){
    int d = ei[E + e];
    int r = 0;
    if ((unsigned)d < (unsigned)n){
      float w = load_w(ew, e, flag[0]);
      unsigned int wq = (unsigned int)(w * WSUM_SCALE + 0.5f);
      unsigned long long pk = (1ull << 40) | (unsigned long long)wq;
      unsigned long long old = atomicAdd(&acc[(size_t)d*ACCS], pk);
      r = (int)(old >> 40);
    }
    rank[e] = r;
  }
}

__global__ void k_scan1(const unsigned long long* __restrict__ acc,
                        int* __restrict__ bsum, int n){
  int i = blockIdx.x*256 + threadIdx.x;
  int lane = threadIdx.x & 63, w = threadIdx.x >> 6;
  int v = (i < n) ? (int)(acc[(size_t)i*ACCS] >> 40) + 1 : 0;
  for (int off = 32; off; off >>= 1) v += __shfl_down(v, off);
  __shared__ int ws[4];
  if (lane == 0) ws[w] = v;
  __syncthreads();
  if (threadIdx.x == 0) bsum[blockIdx.x] = ws[0] + ws[1] + ws[2] + ws[3];
}

// fused scan phases 2+3: each block reduces bsum[0..b) inline, then scans its chunk
__global__ void k_scan3(const unsigned long long* __restrict__ acc,
                        const int* __restrict__ bsum,
                        int* __restrict__ rowptr, int n, int nB){
  int b = blockIdx.x, tid = threadIdx.x;
  int lane = tid & 63, w = tid >> 6;
  __shared__ int ws[4];
  __shared__ int sboff;

  int part = 0;
  for (int t = tid; t < b; t += 256) part += bsum[t];
  for (int off = 32; off; off >>= 1) part += __shfl_down(part, off);
  if (lane == 0) ws[w] = part;
  __syncthreads();
  if (tid == 0) sboff = ws[0] + ws[1] + ws[2] + ws[3];
  __syncthreads();
  int boff = sboff;
  __syncthreads();

  int i = b*256 + tid;
  int v = (i < n) ? (int)(acc[(size_t)i*ACCS] >> 40) + 1 : 0;
  int sv = v;
  for (int off = 1; off < 64; off <<= 1){
    int t = __shfl_up(sv, off);
    if (lane >= off) sv += t;
  }
  if (lane == 63) ws[w] = sv;
  __syncthreads();
  if (tid == 0){
    int acc2 = 0;
    for (int k = 0; k < 4; k++){ int t = ws[k]; ws[k] = acc2; acc2 += t; }
  }
  __syncthreads();
  if (i < n) rowptr[i + 1] = boff + ws[w] + sv;
  if (i == 0) rowptr[0] = 0;
  (void)nB;
}

// fused: ATOMIC-FREE scatter (blocks [0,Eb)) + self-loop write (blocks [Eb,..)).
// Independent: scatter fills slots < endv-1, selfw writes slot endv-1.
__global__ void k_scat_self(const int* __restrict__ ei, const void* __restrict__ ew,
                            const int* __restrict__ rank, const int* __restrict__ rowptr,
                            const unsigned long long* __restrict__ acc,
                            uint2* __restrict__ csr,
                            int E, int n, int ET, const int* __restrict__ flag, int Eb){
  int b = blockIdx.x;
  if (b < Eb){
    int e = b*256 + threadIdx.x;
    if (e < E){
      int s = ei[e], d = ei[E + e];
      if ((unsigned)d < (unsigned)n){
        int pos = rowptr[d] + rank[e];
        if ((unsigned)pos < (unsigned)ET){
          float w = load_w(ew, e, flag[0]);
          csr[pos] = make_uint2((unsigned)s, __builtin_bit_cast(unsigned, w));
        }
      }
    }
  } else {
    int i = (b - Eb)*256 + threadIdx.x;
    if (i < n){
      int beg = rowptr[i], endv = rowptr[i+1];
      int deg = endv - 1 - beg;
      float ws = (float)(acc[(size_t)i*ACCS] & WSUM_MASK) * WSUM_INV;
      float w = ws / fmaxf((float)deg, 1.0f);
      csr[endv - 1] = make_uint2((unsigned)i, __builtin_bit_cast(unsigned, w));
    }
  }
}

// ---------------- GEMM: xl (bf16 out) and xr (f32 out) in one launch ----------------
// 16 rows per wave: high wave count for latency hiding.

template<int NC>
__global__ __launch_bounds__(64) void k_gemm2(
  const unsigned short* __restrict__ A,
  const unsigned short* __restrict__ WTl, const unsigned short* __restrict__ WTr,
  const float* __restrict__ bl, const float* __restrict__ br,
  unsigned short* __restrict__ outL, float* __restrict__ outR,
  int nrows)
{
  constexpr int CT = NC / 16;
  int lane = threadIdx.x;
  int q = lane >> 4, rr = lane & 15;
  int r0 = blockIdx.x * 16;
  bool isR = blockIdx.y == 1;
  const unsigned short* WT = isR ? WTr : WTl;
  const float* bia         = isR ? br  : bl;

  f32x4 acc[CT];
  #pragma unroll
  for (int b = 0; b < CT; b++) acc[b] = (f32x4){0.f, 0.f, 0.f, 0.f};

  int row = r0 + rr;
  if (row >= nrows) row = nrows - 1;

  #pragma unroll
  for (int kc = 0; kc < 4; kc++){
    bf16x8 af = *(const bf16x8*)(A + (size_t)row*128 + kc*32 + q*8);
    #pragma unroll
    for (int ct = 0; ct < CT; ct++){
      bf16x8 bfr = *(const bf16x8*)(WT + (size_t)(ct*16 + rr)*128 + kc*32 + q*8);
      acc[ct] = __builtin_amdgcn_mfma_f32_16x16x32_bf16(af, bfr, acc[ct], 0, 0, 0);
    }
  }

  // C/D layout: col = lane&15, row = (lane>>4)*4 + reg
  #pragma unroll
  for (int ct = 0; ct < CT; ct++){
    int col = ct*16 + rr;
    float bv = bia[col];
    #pragma unroll
    for (int t = 0; t < 4; t++){
      int orow = r0 + q*4 + t;
      if (orow < nrows){
        float v = acc[ct][t] + bv;
        if (isR) outR[(size_t)orow*NC + col] = v;
        else     outL[(size_t)orow*NC + col] = f2bf(v);
      }
    }
  }
}

// ---------------- fused edge scoring + online-softmax aggregation ----------------
// [round-3 proven bodies — round-4 packed-f32 rewrite REGRESSED (VALU time up,
// occupancy down), reverted] readfirstlane-scalarized csr fetch, |t| leakyrelu
// fold, ds_swizzle reductions, 8-edge SGPR block prefetch.

__global__ __launch_bounds__(256) void k_edge128(
  const unsigned short* __restrict__ xl, const float* __restrict__ xr,
  const int* __restrict__ rowptr, const uint2* __restrict__ csr,
  const float* __restrict__ We, const float* __restrict__ att,
  const float* __restrict__ bias, unsigned short* __restrict__ out, int n, int ET)
{
  int wid = threadIdx.x >> 6;
  int lane = threadIdx.x & 63;
  int node = __builtin_amdgcn_readfirstlane(blockIdx.x*4 + wid);
  if (node >= n) return;
  int ch = lane*2;
  float we0 = We[ch],  we1 = We[ch+1];
  float at0 = att[ch], at1 = att[ch+1];   // pre-scaled by log2e
  float c10 = 0.6f*at0, c20 = 0.4f*at0;
  float c11 = 0.6f*at1, c21 = 0.4f*at1;
  float2 xrv = *(const float2*)(xr + (size_t)node*128 + ch);
  float fxr0 = xrv.x, fxr1 = xrv.y;
  int beg = rowptr[node], end = rowptr[node+1];
  if (beg < 0) beg = 0;
  if (end > ET) end = ET;
  float m = -1e30f, l = 0.f, a0 = 0.f, a1 = 0.f;

  auto loadblk = [&](int base, int* S, float* W){
    #pragma unroll
    for (int j = 0; j < 8; j++){
      uint2 pk = csr[base + j];          // uniform addr -> s_load
      int sv = (int)pk.x;
      if ((unsigned)sv >= (unsigned)n) sv = 0;
      S[j] = sv;
      W[j] = __builtin_bit_cast(float, pk.y);
    }
  };

  int i = beg;
  int sc_[8]; float wc_[8];
  bool have = (i + 8 <= end);
  if (have) loadblk(i, sc_, wc_);
  while (have){
    unsigned u[8];
    #pragma unroll
    for (int j = 0; j < 8; j++){
      const unsigned short* rp = xl + (size_t)sc_[j]*128;   // scalar base
      u[j] = *(const unsigned int*)(rp + ch);               // saddr + v_ch
    }
    bool hnext = (i + 16 <= end);
    int sn_[8]; float wn_[8];
    if (hnext) loadblk(i + 8, sn_, wn_);    // prefetch next block

    float vx[8], vy[8], pp[8];
    #pragma unroll
    for (int j = 0; j < 8; j++){
      vx[j] = __builtin_bit_cast(float, u[j] << 16);
      vy[j] = __builtin_bit_cast(float, u[j] & 0xffff0000u);
      float t0 = fmaf(wc_[j], we0, fxr0) + vx[j];
      float t1 = fmaf(wc_[j], we1, fxr1) + vy[j];
      float p  = fmaf(c10, t0, c20*fabsf(t0));
      p        = fmaf(c11, t1, fmaf(c21, fabsf(t1), p));
      pp[j] = sum16(p);
    }
    float mx = fmaxf(fmaxf(fmaxf(pp[0], pp[1]), fmaxf(pp[2], pp[3])),
                     fmaxf(fmaxf(pp[4], pp[5]), fmaxf(pp[6], pp[7])));
    float nm = fmaxf(m, mx);
    float sc = exp2f(m - nm);
    float el = 0.f, ea0 = 0.f, ea1 = 0.f;
    #pragma unroll
    for (int j = 0; j < 8; j++){
      float e = exp2f(pp[j] - nm);
      el  += e;
      ea0 += e*vx[j];
      ea1 += e*vy[j];
    }
    l  = l*sc  + el;
    a0 = a0*sc + ea0;
    a1 = a1*sc + ea1;
    m = nm;
    i += 8;
    have = hnext;
    if (have){
      #pragma unroll
      for (int j = 0; j < 8; j++){ sc_[j] = sn_[j]; wc_[j] = wn_[j]; }
    }
  }
  for (; i < end; i++){
    uint2 pk = csr[i];
    int sv = (int)pk.x;
    if ((unsigned)sv >= (unsigned)n) sv = 0;
    float w = __builtin_bit_cast(float, pk.y);
    const unsigned short* rp = xl + (size_t)sv*128;
    unsigned u = *(const unsigned int*)(rp + ch);
    float x0 = __builtin_bit_cast(float, u << 16);
    float x1 = __builtin_bit_cast(float, u & 0xffff0000u);
    float t0 = fmaf(w, we0, fxr0) + x0;
    float t1 = fmaf(w, we1, fxr1) + x1;
    float p  = fmaf(c10, t0, c20*fabsf(t0));
    p        = fmaf(c11, t1, fmaf(c21, fabsf(t1), p));
    p = sum16(p);
    float nm = fmaxf(m, p);
    float scv = exp2f(m - nm);
    float pe  = exp2f(p - nm);
    l  = l*scv  + pe;
    a0 = a0*scv + pe*x0;
    a1 = a1*scv + pe*x1;
    m = nm;
  }
  float inv = 1.0f / (l + 1e-16f);
  float o0 = a0*inv + bias[ch];
  float o1 = a1*inv + bias[ch+1];
  o0 = o0 > 0.f ? o0 : (__expf(o0) - 1.0f);   // ELU (layers 0,1)
  o1 = o1 > 0.f ? o1 : (__expf(o1) - 1.0f);
  unsigned int packed = (unsigned int)f2bf(o0) | ((unsigned int)f2bf(o1) << 16);
  *(unsigned int*)(out + (size_t)node*128 + ch) = packed;
}

__global__ __launch_bounds__(256) void k_edge64(
  const unsigned short* __restrict__ xl, const float* __restrict__ xr,
  const int* __restrict__ rowptr, const uint2* __restrict__ csr,
  const float* __restrict__ We, const float* __restrict__ att,
  const float* __restrict__ bias, void* __restrict__ out, int n, int ET,
  const int* __restrict__ flag)
{
  int wid = threadIdx.x >> 6;
  int lane = threadIdx.x & 63;
  int node = __builtin_amdgcn_readfirstlane(blockIdx.x*4 + wid);
  if (node >= n) return;
  float we0 = We[lane];
  float at0 = att[lane];          // pre-scaled by log2e
  float c1 = 0.6f*at0, c2 = 0.4f*at0;
  float fxr0 = xr[(size_t)node*64 + lane];
  int bpa = ((lane ^ 32) << 2);
  int beg = rowptr[node], end = rowptr[node+1];
  if (beg < 0) beg = 0;
  if (end > ET) end = ET;
  float m = -1e30f, l = 0.f, a0 = 0.f;

  auto loadblk = [&](int base, int* S, float* W){
    #pragma unroll
    for (int j = 0; j < 8; j++){
      uint2 pk = csr[base + j];
      int sv = (int)pk.x;
      if ((unsigned)sv >= (unsigned)n) sv = 0;
      S[j] = sv;
      W[j] = __builtin_bit_cast(float, pk.y);
    }
  };

  int i = beg;
  int sc_[8]; float wc_[8];
  bool have = (i + 8 <= end);
  if (have) loadblk(i, sc_, wc_);
  while (have){
    float x[8];
    #pragma unroll
    for (int j = 0; j < 8; j++){
      const unsigned short* rp = xl + (size_t)sc_[j]*64;
      x[j] = bf2f(rp[lane]);
    }
    bool hnext = (i + 16 <= end);
    int sn_[8]; float wn_[8];
    if (hnext) loadblk(i + 8, sn_, wn_);

    float pp[8];
    #pragma unroll
    for (int j = 0; j < 8; j++){
      float t = fmaf(wc_[j], we0, fxr0) + x[j];
      float p = fmaf(c1, t, c2*fabsf(t));
      pp[j] = sum64(p, bpa);
    }
    float mx = fmaxf(fmaxf(fmaxf(pp[0], pp[1]), fmaxf(pp[2], pp[3])),
                     fmaxf(fmaxf(pp[4], pp[5]), fmaxf(pp[6], pp[7])));
    float nm = fmaxf(m, mx);
    float sc = exp2f(m - nm);
    float el = 0.f, ea = 0.f;
    #pragma unroll
    for (int j = 0; j < 8; j++){
      float e = exp2f(pp[j] - nm);
      el += e;
      ea += e*x[j];
    }
    l  = l*sc  + el;
    a0 = a0*sc + ea;
    m = nm;
    i += 8;
    have = hnext;
    if (have){
      #pragma unroll
      for (int j = 0; j < 8; j++){ sc_[j] = sn_[j]; wc_[j] = wn_[j]; }
    }
  }
  for (; i < end; i++){
    uint2 pk = csr[i];
    int sv = (int)pk.x;
    if ((unsigned)sv >= (unsigned)n) sv = 0;
    float w = __builtin_bit_cast(float, pk.y);
    float x0 = bf2f(xl[(size_t)sv*64 + lane]);
    float t0 = fmaf(w, we0, fxr0) + x0;
    float p  = fmaf(c1, t0, c2*fabsf(t0));
    p = sum64(p, bpa);
    float nm = fmaxf(m, p);
    float scv = exp2f(m - nm);
    float pe  = exp2f(p - nm);
    l  = l*scv  + pe;
    a0 = a0*scv + pe*x0;
    m = nm;
  }
  float inv = 1.0f / (l + 1e-16f);
  float res = a0*inv + bias[lane];
  size_t oi = (size_t)node*64 + lane;
  if (flag[0]) ((float*)out)[oi] = res;
  else         ((unsigned short*)out)[oi] = f2bf(res);
}

// ---------------- host ----------------

extern "C" void kernel_launch(void* const* d_in, const int* in_sizes, int n_in,
                              void* d_out, int out_size, void* d_ws, size_t ws_size,
                              hipStream_t stream)
{
  (void)n_in; (void)out_size; (void)ws_size;
  const void* x   = d_in[0];
  const int*  ei  = (const int*)d_in[1];
  const void* ew  = d_in[2];

  const int N = in_sizes[0] / 128;
  const int E = in_sizes[2];
  const int ET = E + N;
  const int nB = (N + 255) / 256;

  char* p = (char*)d_ws;
  size_t off = 0;
  auto carve = [&](size_t bytes)->void* {
    void* r = p + off;
    off = (off + bytes + 255) & ~(size_t)255;
    return r;
  };
  int*                flag   = (int*)carve(4);
  unsigned long long* acc    = (unsigned long long*)carve((size_t)N*ACCS*8);  // 128B/node
  int*                rowptr = (int*)carve((size_t)(N+1)*4);
  int*                bsum   = (int*)carve((size_t)nB*4);
  int*                rank   = (int*)carve((size_t)E*4);
  uint2*              csr    = (uint2*)carve((size_t)ET*8);
  float*              prm    = (float*)carve(15*128*4);
  unsigned short*     WT0l   = (unsigned short*)carve(128*128*2);
  unsigned short*     WT0r   = (unsigned short*)carve(128*128*2);
  unsigned short*     WT1l   = (unsigned short*)carve(128*128*2);
  unsigned short*     WT1r   = (unsigned short*)carve(128*128*2);
  unsigned short*     WT2l   = (unsigned short*)carve(128*64*2);
  unsigned short*     WT2r   = (unsigned short*)carve(128*64*2);
  unsigned short*     xc     = (unsigned short*)carve((size_t)N*128*2);
  unsigned short*     xlb16  = (unsigned short*)carve((size_t)N*128*2);
  float*              xrb    = (float*)carve((size_t)N*128*4);
  unsigned short*     hb     = (unsigned short*)carve((size_t)N*128*2);

  float* bl0c = prm + 0*128;  float* br0c = prm + 1*128;
  float* We0c = prm + 2*128;  float* at0c = prm + 3*128;  float* bi0c = prm + 4*128;
  float* bl1c = prm + 5*128;  float* br1c = prm + 6*128;
  float* We1c = prm + 7*128;  float* at1c = prm + 8*128;  float* bi1c = prm + 9*128;
  float* bl2c = prm + 10*128; float* br2c = prm + 11*128;
  float* We2c = prm + 12*128; float* at2c = prm + 13*128; float* bi2c = prm + 14*128;

  const float LOG2E = 1.4426950408889634f;
  MegaArgs ma;
  {
    const void* srcs[15] = { d_in[4], d_in[6], d_in[7], d_in[8], d_in[9],
                             d_in[11], d_in[13], d_in[14], d_in[15], d_in[16],
                             d_in[18], d_in[20], d_in[21], d_in[22], d_in[23] };
    float* dsts[15] = { bl0c, br0c, We0c, at0c, bi0c,
                        bl1c, br1c, We1c, at1c, bi1c,
                        bl2c, br2c, We2c, at2c, bi2c };
    int ns[15] = {128,128,128,128,128, 128,128,128,128,128, 64,64,64,64,64};
    for (int i = 0; i < 15; i++){
      ma.psrc[i] = srcs[i]; ma.pdst[i] = dsts[i]; ma.pn[i] = ns[i];
      ma.pscale[i] = (i == 3 || i == 8 || i == 13) ? LOG2E : 1.0f;  // att slots
    }
    const void* wsrcs[6] = { d_in[3], d_in[5], d_in[10], d_in[12], d_in[17], d_in[19] };
    unsigned short* wdsts[6] = { WT0l, WT0r, WT1l, WT1r, WT2l, WT2r };
    int Ms[6] = {128, 128, 128, 128, 64, 64};
    for (int i = 0; i < 6; i++){ ma.wsrc[i] = wsrcs[i]; ma.wdst[i] = wdsts[i]; ma.wM[i] = Ms[i]; }
    ma.x = x; ma.xc = xc; ma.n4 = N*32;
    ma.cnt = (int*)acc; ma.nz4 = N*ACCS/2;   // N*128 bytes in int4 granules
    ma.flag = flag;
  }
  int xB = (ma.n4 + 255) / 256;
  int zB = (ma.nz4 + 255) / 256;
  k_mega<<<1 + 320 + xB + zB, 256, 0, stream>>>(ma);

  // graph build: ONE u64 atomic/edge (hist+rank+wsum) on 128B-padded acc,
  // 2-launch scan, fused atomic-free scatter + self-loop write
  const int Eb = (E + 255) / 256;
  k_hist <<<Eb, 256, 0, stream>>>(ei, ew, acc, rank, E, N, flag);
  k_scan1<<<nB, 256, 0, stream>>>(acc, bsum, N);
  k_scan3<<<nB, 256, 0, stream>>>(acc, bsum, rowptr, N, nB);
  k_scat_self<<<Eb + nB, 256, 0, stream>>>(ei, ew, rank, rowptr, acc, csr, E, N, ET, flag, Eb);

  const int rowBlocks = (N + 15) / 16;

  // layer 0
  k_gemm2<128><<<dim3(rowBlocks, 2), 64, 0, stream>>>(xc, WT0l, WT0r, bl0c, br0c, xlb16, xrb, N);
  k_edge128<<<(N+3)/4, 256, 0, stream>>>(xlb16, xrb, rowptr, csr, We0c, at0c, bi0c, hb, N, ET);

  // layer 1
  k_gemm2<128><<<dim3(rowBlocks, 2), 64, 0, stream>>>(hb, WT1l, WT1r, bl1c, br1c, xlb16, xrb, N);
  k_edge128<<<(N+3)/4, 256, 0, stream>>>(xlb16, xrb, rowptr, csr, We1c, at1c, bi1c, hb, N, ET);

  // layer 2
  k_gemm2<64><<<dim3(rowBlocks, 2), 64, 0, stream>>>(hb, WT2l, WT2r, bl2c, br2c, xlb16, xrb, N);
  k_edge64<<<(N+3)/4, 256, 0, stream>>>(xlb16, xrb, rowptr, csr, We2c, at2c, bi2c,
                                        d_out, N, ET, flag);
}

// Round 7
// 406.131 us; speedup vs baseline: 1.0503x; 1.0248x over previous
//
#include <hip/hip_runtime.h>
#include <cstdint>
#include <cstddef>

typedef __bf16 bf16x8 __attribute__((ext_vector_type(8)));
typedef float f32x4 __attribute__((ext_vector_type(4)));

__device__ __forceinline__ float bf2f(unsigned short u){
  unsigned int x = ((unsigned int)u) << 16;
  return __builtin_bit_cast(float, x);
}
__device__ __forceinline__ unsigned short f2bf(float f){
  unsigned int x = __builtin_bit_cast(unsigned int, f);
  x += 0x7fffu + ((x >> 16) & 1u);
  return (unsigned short)(x >> 16);
}

// ---- cross-lane reductions on the (idle) LDS pipe: ds_swizzle butterflies ----
template<int P> __device__ __forceinline__ float swz_add(float x){
  int y = __builtin_amdgcn_ds_swizzle(__builtin_bit_cast(int, x), P);
  return x + __builtin_bit_cast(float, y);
}
__device__ __forceinline__ float sum16(float x){
  x = swz_add<0x041F>(x);   // xor 1  (BitMode: and=0x1F, or=0, xor=k)
  x = swz_add<0x081F>(x);   // xor 2
  x = swz_add<0x101F>(x);   // xor 4
  x = swz_add<0x201F>(x);   // xor 8
  return x;
}
__device__ __forceinline__ float sum64(float x, int bpa){
  x = swz_add<0x041F>(x);
  x = swz_add<0x081F>(x);
  x = swz_add<0x101F>(x);
  x = swz_add<0x201F>(x);
  x = swz_add<0x401F>(x);   // xor 16 (within 32-lane group)
  int y = __builtin_amdgcn_ds_bpermute(bpa, __builtin_bit_cast(int, x)); // lane^32
  return x + __builtin_bit_cast(float, y);
}

__device__ __forceinline__ float load_w(const void* ew, int e, int f){
  return f ? ((const float*)ew)[e] : bf2f(((const unsigned short*)ew)[e]);
}

// fixed-point packing for the 64b atomic (per-shard):
//   acc[d*NSH + (e&3)] += (1<<40) | round(w * 2^24)
// high 24 bits = shard count (old>>40 == shard-local rank), low 40 = wsum 2^-24.
// NSH=4 shards: same-address atomic chain drops ~16 -> ~4 (round-5 showed
// padding/false-sharing is NOT the issue; same-address serialization is).
#define WSUM_MASK  ((1ull << 40) - 1ull)
#define WSUM_SCALE 16777216.0f
#define WSUM_INV   (1.0f / 16777216.0f)
#define NSH 4

// ---------------- mega canon kernel ----------------
// One launch: per-block dtype flag (256-short probe of x), param canon,
// weight transpose canon, x->bf16 canon, acc zeroing. Block ranges:
//   [0]                 params + flag store
//   [1, 321)            weight tensors (64,64,64,64,32,32 blocks)
//   [321, 321+xB)       x canon (ushort4 granules)
//   [321+xB, ...)       acc zero (int4 granules)

struct MegaArgs {
  const void* psrc[15]; float* pdst[15]; int pn[15]; float pscale[15];
  const void* wsrc[6]; unsigned short* wdst[6]; int wM[6];
  const void* x; unsigned short* xc; int n4;
  int* cnt; int nz4;
  int* flag;
};

__global__ __launch_bounds__(256) void k_mega(MegaArgs a){
  __shared__ int sf;
  if (threadIdx.x == 0) sf = 0;
  __syncthreads();
  {
    unsigned short u = ((const unsigned short*)a.x)[threadIdx.x];
    int expo = (u >> 7) & 0xFF;
    if (expo >= 0xC0) atomicOr(&sf, 1);
  }
  __syncthreads();
  int f = sf;
  int b = blockIdx.x;

  if (b == 0){
    if (threadIdx.x == 0) a.flag[0] = f;
    for (int t = 0; t < 15; t++){
      int i = threadIdx.x;
      if (i < a.pn[t]){
        float v = f ? ((const float*)a.psrc[t])[i]
                    : bf2f(((const unsigned short*)a.psrc[t])[i]);
        a.pdst[t][i] = v * a.pscale[t];
      }
    }
    return;
  }
  b -= 1;
  if (b < 320){
    int t, base;
    if      (b <  64){ t = 0; base = b;       }
    else if (b < 128){ t = 1; base = b - 64;  }
    else if (b < 192){ t = 2; base = b - 128; }
    else if (b < 256){ t = 3; base = b - 192; }
    else if (b < 288){ t = 4; base = b - 256; }
    else             { t = 5; base = b - 288; }
    int M = a.wM[t];
    int idx = base*256 + threadIdx.x;
    if (idx < 128*M){
      int k = idx / M, m2 = idx % M;
      unsigned short v = f ? f2bf(((const float*)a.wsrc[t])[idx])
                           : ((const unsigned short*)a.wsrc[t])[idx];
      a.wdst[t][m2*128 + k] = v;
    }
    return;
  }
  b -= 320;
  int xB = (a.n4 + 255) / 256;
  if (b < xB){
    int i = b*256 + threadIdx.x;
    if (i < a.n4){
      if (f){
        float4 v = ((const float4*)a.x)[i];
        ushort4 o;
        o.x = f2bf(v.x); o.y = f2bf(v.y); o.z = f2bf(v.z); o.w = f2bf(v.w);
        ((ushort4*)a.xc)[i] = o;
      } else {
        ((ushort4*)a.xc)[i] = ((const ushort4*)a.x)[i];
      }
    }
    return;
  }
  b -= xB;
  int i = b*256 + threadIdx.x;
  if (i < a.nz4) ((int4*)a.cnt)[i] = make_int4(0, 0, 0, 0);
}

// ---------------- fused: layer-0 GEMM + sharded hist ----------------
// blocks [0, gB): gemm layer-0 (4 row-tile waves per block, L+R halves);
// blocks [gB, ..): hist (1 packed u64 atomic per edge, 4-shard).
// Independent data; hist is atomic-latency-bound with idle VALU/MFMA, the
// co-resident gemm waves use those pipes (same-stream kernels serialize,
// so overlap requires one launch).

__global__ __launch_bounds__(256) void k_histgemm(
  const unsigned short* __restrict__ A,
  const unsigned short* __restrict__ WTl, const unsigned short* __restrict__ WTr,
  const float* __restrict__ bl, const float* __restrict__ br,
  unsigned short* __restrict__ outL, float* __restrict__ outR,
  int nrows, int rowBlocks, int gB,
  const int* __restrict__ ei, const void* __restrict__ ew,
  unsigned long long* __restrict__ acc,
  int* __restrict__ rank, int E, int n, const int* __restrict__ flag)
{
  int b = blockIdx.x;
  if (b < gB){
    int wid = threadIdx.x >> 6;
    int t = b*4 + wid;
    if (t >= 2*rowBlocks) return;
    bool isR = t >= rowBlocks;
    int r0 = (isR ? t - rowBlocks : t) * 16;
    const unsigned short* WT = isR ? WTr : WTl;
    const float* bia         = isR ? br  : bl;
    int lane = threadIdx.x & 63;
    int q = lane >> 4, rr = lane & 15;

    f32x4 ac[8];
    #pragma unroll
    for (int c = 0; c < 8; c++) ac[c] = (f32x4){0.f, 0.f, 0.f, 0.f};
    int row = r0 + rr;
    if (row >= nrows) row = nrows - 1;
    #pragma unroll
    for (int kc = 0; kc < 4; kc++){
      bf16x8 af = *(const bf16x8*)(A + (size_t)row*128 + kc*32 + q*8);
      #pragma unroll
      for (int ct = 0; ct < 8; ct++){
        bf16x8 bfr = *(const bf16x8*)(WT + (size_t)(ct*16 + rr)*128 + kc*32 + q*8);
        ac[ct] = __builtin_amdgcn_mfma_f32_16x16x32_bf16(af, bfr, ac[ct], 0, 0, 0);
      }
    }
    #pragma unroll
    for (int ct = 0; ct < 8; ct++){
      int col = ct*16 + rr;
      float bv = bia[col];
      #pragma unroll
      for (int t4 = 0; t4 < 4; t4++){
        int orow = r0 + q*4 + t4;
        if (orow < nrows){
          float v = ac[ct][t4] + bv;
          if (isR) outR[(size_t)orow*128 + col] = v;
          else     outL[(size_t)orow*128 + col] = f2bf(v);
        }
      }
    }
    return;
  }
  int e = (b - gB)*256 + threadIdx.x;
  if (e < E){
    int d = ei[E + e];
    int r = 0;
    if ((unsigned)d < (unsigned)n){
      float w = load_w(ew, e, flag[0]);
      unsigned int wq = (unsigned int)(w * WSUM_SCALE + 0.5f);
      unsigned long long pk = (1ull << 40) | (unsigned long long)wq;
      int k = e & (NSH - 1);
      unsigned long long old = atomicAdd(&acc[(size_t)d*NSH + k], pk);
      r = (int)(old >> 40);
    }
    rank[e] = r;
  }
}

__global__ void k_scan1(const unsigned long long* __restrict__ acc,
                        int* __restrict__ bsum, int n){
  int i = blockIdx.x*256 + threadIdx.x;
  int lane = threadIdx.x & 63, w = threadIdx.x >> 6;
  int v = 0;
  if (i < n){
    const ulonglong2* a2 = (const ulonglong2*)(acc + (size_t)i*NSH);
    ulonglong2 p0 = a2[0], p1 = a2[1];
    v = (int)((p0.x >> 40) + (p0.y >> 40) + (p1.x >> 40) + (p1.y >> 40)) + 1;
  }
  for (int off = 32; off; off >>= 1) v += __shfl_down(v, off);
  __shared__ int ws[4];
  if (lane == 0) ws[w] = v;
  __syncthreads();
  if (threadIdx.x == 0) bsum[blockIdx.x] = ws[0] + ws[1] + ws[2] + ws[3];
}

// fused scan phases 2+3; also emits per-node shard prefix (pso)
__global__ void k_scan3(const unsigned long long* __restrict__ acc,
                        const int* __restrict__ bsum,
                        int* __restrict__ rowptr, ushort4* __restrict__ pso,
                        int n, int nB){
  int b = blockIdx.x, tid = threadIdx.x;
  int lane = tid & 63, w = tid >> 6;
  __shared__ int ws[4];
  __shared__ int sboff;

  int part = 0;
  for (int t = tid; t < b; t += 256) part += bsum[t];
  for (int off = 32; off; off >>= 1) part += __shfl_down(part, off);
  if (lane == 0) ws[w] = part;
  __syncthreads();
  if (tid == 0) sboff = ws[0] + ws[1] + ws[2] + ws[3];
  __syncthreads();
  int boff = sboff;
  __syncthreads();

  int i = b*256 + tid;
  int v = 0;
  if (i < n){
    const ulonglong2* a2 = (const ulonglong2*)(acc + (size_t)i*NSH);
    ulonglong2 p0 = a2[0], p1 = a2[1];
    int c0 = (int)(p0.x >> 40), c1 = (int)(p0.y >> 40);
    int c2 = (int)(p1.x >> 40), c3 = (int)(p1.y >> 40);
    v = c0 + c1 + c2 + c3 + 1;
    ushort4 o;
    o.x = 0;
    o.y = (unsigned short)c0;
    o.z = (unsigned short)(c0 + c1);
    o.w = (unsigned short)(c0 + c1 + c2);
    pso[i] = o;
  }
  int sv = v;
  for (int off = 1; off < 64; off <<= 1){
    int t = __shfl_up(sv, off);
    if (lane >= off) sv += t;
  }
  if (lane == 63) ws[w] = sv;
  __syncthreads();
  if (tid == 0){
    int acc2 = 0;
    for (int k = 0; k < 4; k++){ int t = ws[k]; ws[k] = acc2; acc2 += t; }
  }
  __syncthreads();
  if (i < n) rowptr[i + 1] = boff + ws[w] + sv;
  if (i == 0) rowptr[0] = 0;
  (void)nB;
}

// fused: ATOMIC-FREE scatter (blocks [0,Eb)) + self-loop write (blocks [Eb,..)).
// pos = rowptr[d] + shardPrefix[d][e&3] + shard-local rank.
__global__ void k_scat_self(const int* __restrict__ ei, const void* __restrict__ ew,
                            const int* __restrict__ rank, const int* __restrict__ rowptr,
                            const unsigned long long* __restrict__ acc,
                            const ushort4* __restrict__ pso,
                            uint2* __restrict__ csr,
                            int E, int n, int ET, const int* __restrict__ flag, int Eb){
  int b = blockIdx.x;
  if (b < Eb){
    int e = b*256 + threadIdx.x;
    if (e < E){
      int s = ei[e], d = ei[E + e];
      if ((unsigned)d < (unsigned)n){
        int k = e & (NSH - 1);
        uint2 ps = *(const uint2*)(pso + d);
        unsigned off = (k & 2) ? ps.y : ps.x;
        off = (off >> ((k & 1) * 16)) & 0xffffu;
        int pos = rowptr[d] + (int)off + rank[e];
        if ((unsigned)pos < (unsigned)ET){
          float w = load_w(ew, e, flag[0]);
          csr[pos] = make_uint2((unsigned)s, __builtin_bit_cast(unsigned, w));
        }
      }
    }
  } else {
    int i = (b - Eb)*256 + threadIdx.x;
    if (i < n){
      int beg = rowptr[i], endv = rowptr[i+1];
      int deg = endv - 1 - beg;
      const ulonglong2* a2 = (const ulonglong2*)(acc + (size_t)i*NSH);
      ulonglong2 p0 = a2[0], p1 = a2[1];
      float ws = (float)((p0.x & WSUM_MASK) + (p0.y & WSUM_MASK) +
                         (p1.x & WSUM_MASK) + (p1.y & WSUM_MASK)) * WSUM_INV;
      float w = ws / fmaxf((float)deg, 1.0f);
      csr[endv - 1] = make_uint2((unsigned)i, __builtin_bit_cast(unsigned, w));
    }
  }
}

// ---------------- GEMM (layers 1,2): xl (bf16) and xr (f32) in one launch ----------------

template<int NC>
__global__ __launch_bounds__(64) void k_gemm2(
  const unsigned short* __restrict__ A,
  const unsigned short* __restrict__ WTl, const unsigned short* __restrict__ WTr,
  const float* __restrict__ bl, const float* __restrict__ br,
  unsigned short* __restrict__ outL, float* __restrict__ outR,
  int nrows)
{
  constexpr int CT = NC / 16;
  int lane = threadIdx.x;
  int q = lane >> 4, rr = lane & 15;
  int r0 = blockIdx.x * 16;
  bool isR = blockIdx.y == 1;
  const unsigned short* WT = isR ? WTr : WTl;
  const float* bia         = isR ? br  : bl;

  f32x4 acc[CT];
  #pragma unroll
  for (int b = 0; b < CT; b++) acc[b] = (f32x4){0.f, 0.f, 0.f, 0.f};

  int row = r0 + rr;
  if (row >= nrows) row = nrows - 1;

  #pragma unroll
  for (int kc = 0; kc < 4; kc++){
    bf16x8 af = *(const bf16x8*)(A + (size_t)row*128 + kc*32 + q*8);
    #pragma unroll
    for (int ct = 0; ct < CT; ct++){
      bf16x8 bfr = *(const bf16x8*)(WT + (size_t)(ct*16 + rr)*128 + kc*32 + q*8);
      acc[ct] = __builtin_amdgcn_mfma_f32_16x16x32_bf16(af, bfr, acc[ct], 0, 0, 0);
    }
  }

  // C/D layout: col = lane&15, row = (lane>>4)*4 + reg
  #pragma unroll
  for (int ct = 0; ct < CT; ct++){
    int col = ct*16 + rr;
    float bv = bia[col];
    #pragma unroll
    for (int t = 0; t < 4; t++){
      int orow = r0 + q*4 + t;
      if (orow < nrows){
        float v = acc[ct][t] + bv;
        if (isR) outR[(size_t)orow*NC + col] = v;
        else     outL[(size_t)orow*NC + col] = f2bf(v);
      }
    }
  }
}

// ---------------- fused edge scoring + online-softmax aggregation ----------------
// [round-3/5 proven bodies] readfirstlane-scalarized csr fetch, |t| leakyrelu
// fold, ds_swizzle reductions, 8-edge SGPR block prefetch.

__global__ __launch_bounds__(256) void k_edge128(
  const unsigned short* __restrict__ xl, const float* __restrict__ xr,
  const int* __restrict__ rowptr, const uint2* __restrict__ csr,
  const float* __restrict__ We, const float* __restrict__ att,
  const float* __restrict__ bias, unsigned short* __restrict__ out, int n, int ET)
{
  int wid = threadIdx.x >> 6;
  int lane = threadIdx.x & 63;
  int node = __builtin_amdgcn_readfirstlane(blockIdx.x*4 + wid);
  if (node >= n) return;
  int ch = lane*2;
  float we0 = We[ch],  we1 = We[ch+1];
  float at0 = att[ch], at1 = att[ch+1];   // pre-scaled by log2e
  float c10 = 0.6f*at0, c20 = 0.4f*at0;
  float c11 = 0.6f*at1, c21 = 0.4f*at1;
  float2 xrv = *(const float2*)(xr + (size_t)node*128 + ch);
  float fxr0 = xrv.x, fxr1 = xrv.y;
  int beg = rowptr[node], end = rowptr[node+1];
  if (beg < 0) beg = 0;
  if (end > ET) end = ET;
  float m = -1e30f, l = 0.f, a0 = 0.f, a1 = 0.f;

  auto loadblk = [&](int base, int* S, float* W){
    #pragma unroll
    for (int j = 0; j < 8; j++){
      uint2 pk = csr[base + j];          // uniform addr -> s_load
      int sv = (int)pk.x;
      if ((unsigned)sv >= (unsigned)n) sv = 0;
      S[j] = sv;
      W[j] = __builtin_bit_cast(float, pk.y);
    }
  };

  int i = beg;
  int sc_[8]; float wc_[8];
  bool have = (i + 8 <= end);
  if (have) loadblk(i, sc_, wc_);
  while (have){
    unsigned u[8];
    #pragma unroll
    for (int j = 0; j < 8; j++){
      const unsigned short* rp = xl + (size_t)sc_[j]*128;   // scalar base
      u[j] = *(const unsigned int*)(rp + ch);               // saddr + v_ch
    }
    bool hnext = (i + 16 <= end);
    int sn_[8]; float wn_[8];
    if (hnext) loadblk(i + 8, sn_, wn_);    // prefetch next block

    float vx[8], vy[8], pp[8];
    #pragma unroll
    for (int j = 0; j < 8; j++){
      vx[j] = __builtin_bit_cast(float, u[j] << 16);
      vy[j] = __builtin_bit_cast(float, u[j] & 0xffff0000u);
      float t0 = fmaf(wc_[j], we0, fxr0) + vx[j];
      float t1 = fmaf(wc_[j], we1, fxr1) + vy[j];
      float p  = fmaf(c10, t0, c20*fabsf(t0));
      p        = fmaf(c11, t1, fmaf(c21, fabsf(t1), p));
      pp[j] = sum16(p);
    }
    float mx = fmaxf(fmaxf(fmaxf(pp[0], pp[1]), fmaxf(pp[2], pp[3])),
                     fmaxf(fmaxf(pp[4], pp[5]), fmaxf(pp[6], pp[7])));
    float nm = fmaxf(m, mx);
    float sc = exp2f(m - nm);
    float el = 0.f, ea0 = 0.f, ea1 = 0.f;
    #pragma unroll
    for (int j = 0; j < 8; j++){
      float e = exp2f(pp[j] - nm);
      el  += e;
      ea0 += e*vx[j];
      ea1 += e*vy[j];
    }
    l  = l*sc  + el;
    a0 = a0*sc + ea0;
    a1 = a1*sc + ea1;
    m = nm;
    i += 8;
    have = hnext;
    if (have){
      #pragma unroll
      for (int j = 0; j < 8; j++){ sc_[j] = sn_[j]; wc_[j] = wn_[j]; }
    }
  }
  for (; i < end; i++){
    uint2 pk = csr[i];
    int sv = (int)pk.x;
    if ((unsigned)sv >= (unsigned)n) sv = 0;
    float w = __builtin_bit_cast(float, pk.y);
    const unsigned short* rp = xl + (size_t)sv*128;
    unsigned u = *(const unsigned int*)(rp + ch);
    float x0 = __builtin_bit_cast(float, u << 16);
    float x1 = __builtin_bit_cast(float, u & 0xffff0000u);
    float t0 = fmaf(w, we0, fxr0) + x0;
    float t1 = fmaf(w, we1, fxr1) + x1;
    float p  = fmaf(c10, t0, c20*fabsf(t0));
    p        = fmaf(c11, t1, fmaf(c21, fabsf(t1), p));
    p = sum16(p);
    float nm = fmaxf(m, p);
    float scv = exp2f(m - nm);
    float pe  = exp2f(p - nm);
    l  = l*scv  + pe;
    a0 = a0*scv + pe*x0;
    a1 = a1*scv + pe*x1;
    m = nm;
  }
  float inv = 1.0f / (l + 1e-16f);
  float o0 = a0*inv + bias[ch];
  float o1 = a1*inv + bias[ch+1];
  o0 = o0 > 0.f ? o0 : (__expf(o0) - 1.0f);   // ELU (layers 0,1)
  o1 = o1 > 0.f ? o1 : (__expf(o1) - 1.0f);
  unsigned int packed = (unsigned int)f2bf(o0) | ((unsigned int)f2bf(o1) << 16);
  *(unsigned int*)(out + (size_t)node*128 + ch) = packed;
}

__global__ __launch_bounds__(256) void k_edge64(
  const unsigned short* __restrict__ xl, const float* __restrict__ xr,
  const int* __restrict__ rowptr, const uint2* __restrict__ csr,
  const float* __restrict__ We, const float* __restrict__ att,
  const float* __restrict__ bias, void* __restrict__ out, int n, int ET,
  const int* __restrict__ flag)
{
  int wid = threadIdx.x >> 6;
  int lane = threadIdx.x & 63;
  int node = __builtin_amdgcn_readfirstlane(blockIdx.x*4 + wid);
  if (node >= n) return;
  float we0 = We[lane];
  float at0 = att[lane];          // pre-scaled by log2e
  float c1 = 0.6f*at0, c2 = 0.4f*at0;
  float fxr0 = xr[(size_t)node*64 + lane];
  int bpa = ((lane ^ 32) << 2);
  int beg = rowptr[node], end = rowptr[node+1];
  if (beg < 0) beg = 0;
  if (end > ET) end = ET;
  float m = -1e30f, l = 0.f, a0 = 0.f;

  auto loadblk = [&](int base, int* S, float* W){
    #pragma unroll
    for (int j = 0; j < 8; j++){
      uint2 pk = csr[base + j];
      int sv = (int)pk.x;
      if ((unsigned)sv >= (unsigned)n) sv = 0;
      S[j] = sv;
      W[j] = __builtin_bit_cast(float, pk.y);
    }
  };

  int i = beg;
  int sc_[8]; float wc_[8];
  bool have = (i + 8 <= end);
  if (have) loadblk(i, sc_, wc_);
  while (have){
    float x[8];
    #pragma unroll
    for (int j = 0; j < 8; j++){
      const unsigned short* rp = xl + (size_t)sc_[j]*64;
      x[j] = bf2f(rp[lane]);
    }
    bool hnext = (i + 16 <= end);
    int sn_[8]; float wn_[8];
    if (hnext) loadblk(i + 8, sn_, wn_);

    float pp[8];
    #pragma unroll
    for (int j = 0; j < 8; j++){
      float t = fmaf(wc_[j], we0, fxr0) + x[j];
      float p = fmaf(c1, t, c2*fabsf(t));
      pp[j] = sum64(p, bpa);
    }
    float mx = fmaxf(fmaxf(fmaxf(pp[0], pp[1]), fmaxf(pp[2], pp[3])),
                     fmaxf(fmaxf(pp[4], pp[5]), fmaxf(pp[6], pp[7])));
    float nm = fmaxf(m, mx);
    float sc = exp2f(m - nm);
    float el = 0.f, ea = 0.f;
    #pragma unroll
    for (int j = 0; j < 8; j++){
      float e = exp2f(pp[j] - nm);
      el += e;
      ea += e*x[j];
    }
    l  = l*sc  + el;
    a0 = a0*sc + ea;
    m = nm;
    i += 8;
    have = hnext;
    if (have){
      #pragma unroll
      for (int j = 0; j < 8; j++){ sc_[j] = sn_[j]; wc_[j] = wn_[j]; }
    }
  }
  for (; i < end; i++){
    uint2 pk = csr[i];
    int sv = (int)pk.x;
    if ((unsigned)sv >= (unsigned)n) sv = 0;
    float w = __builtin_bit_cast(float, pk.y);
    float x0 = bf2f(xl[(size_t)sv*64 + lane]);
    float t0 = fmaf(w, we0, fxr0) + x0;
    float p  = fmaf(c1, t0, c2*fabsf(t0));
    p = sum64(p, bpa);
    float nm = fmaxf(m, p);
    float scv = exp2f(m - nm);
    float pe  = exp2f(p - nm);
    l  = l*scv  + pe;
    a0 = a0*scv + pe*x0;
    m = nm;
  }
  float inv = 1.0f / (l + 1e-16f);
  float res = a0*inv + bias[lane];
  size_t oi = (size_t)node*64 + lane;
  if (flag[0]) ((float*)out)[oi] = res;
  else         ((unsigned short*)out)[oi] = f2bf(res);
}

// ---------------- host ----------------

extern "C" void kernel_launch(void* const* d_in, const int* in_sizes, int n_in,
                              void* d_out, int out_size, void* d_ws, size_t ws_size,
                              hipStream_t stream)
{
  (void)n_in; (void)out_size; (void)ws_size;
  const void* x   = d_in[0];
  const int*  ei  = (const int*)d_in[1];
  const void* ew  = d_in[2];

  const int N = in_sizes[0] / 128;
  const int E = in_sizes[2];
  const int ET = E + N;
  const int nB = (N + 255) / 256;

  char* p = (char*)d_ws;
  size_t off = 0;
  auto carve = [&](size_t bytes)->void* {
    void* r = p + off;
    off = (off + bytes + 255) & ~(size_t)255;
    return r;
  };
  int*                flag   = (int*)carve(4);
  unsigned long long* acc    = (unsigned long long*)carve((size_t)N*NSH*8); // 32B/node
  ushort4*            pso    = (ushort4*)carve((size_t)N*8);
  int*                rowptr = (int*)carve((size_t)(N+1)*4);
  int*                bsum   = (int*)carve((size_t)nB*4);
  int*                rank   = (int*)carve((size_t)E*4);
  uint2*              csr    = (uint2*)carve((size_t)ET*8);
  float*              prm    = (float*)carve(15*128*4);
  unsigned short*     WT0l   = (unsigned short*)carve(128*128*2);
  unsigned short*     WT0r   = (unsigned short*)carve(128*128*2);
  unsigned short*     WT1l   = (unsigned short*)carve(128*128*2);
  unsigned short*     WT1r   = (unsigned short*)carve(128*128*2);
  unsigned short*     WT2l   = (unsigned short*)carve(128*64*2);
  unsigned short*     WT2r   = (unsigned short*)carve(128*64*2);
  unsigned short*     xc     = (unsigned short*)carve((size_t)N*128*2);
  unsigned short*     xlb16  = (unsigned short*)carve((size_t)N*128*2);
  float*              xrb    = (float*)carve((size_t)N*128*4);
  unsigned short*     hb     = (unsigned short*)carve((size_t)N*128*2);

  float* bl0c = prm + 0*128;  float* br0c = prm + 1*128;
  float* We0c = prm + 2*128;  float* at0c = prm + 3*128;  float* bi0c = prm + 4*128;
  float* bl1c = prm + 5*128;  float* br1c = prm + 6*128;
  float* We1c = prm + 7*128;  float* at1c = prm + 8*128;  float* bi1c = prm + 9*128;
  float* bl2c = prm + 10*128; float* br2c = prm + 11*128;
  float* We2c = prm + 12*128; float* at2c = prm + 13*128; float* bi2c = prm + 14*128;

  const float LOG2E = 1.4426950408889634f;
  MegaArgs ma;
  {
    const void* srcs[15] = { d_in[4], d_in[6], d_in[7], d_in[8], d_in[9],
                             d_in[11], d_in[13], d_in[14], d_in[15], d_in[16],
                             d_in[18], d_in[20], d_in[21], d_in[22], d_in[23] };
    float* dsts[15] = { bl0c, br0c, We0c, at0c, bi0c,
                        bl1c, br1c, We1c, at1c, bi1c,
                        bl2c, br2c, We2c, at2c, bi2c };
    int ns[15] = {128,128,128,128,128, 128,128,128,128,128, 64,64,64,64,64};
    for (int i = 0; i < 15; i++){
      ma.psrc[i] = srcs[i]; ma.pdst[i] = dsts[i]; ma.pn[i] = ns[i];
      ma.pscale[i] = (i == 3 || i == 8 || i == 13) ? LOG2E : 1.0f;  // att slots
    }
    const void* wsrcs[6] = { d_in[3], d_in[5], d_in[10], d_in[12], d_in[17], d_in[19] };
    unsigned short* wdsts[6] = { WT0l, WT0r, WT1l, WT1r, WT2l, WT2r };
    int Ms[6] = {128, 128, 128, 128, 64, 64};
    for (int i = 0; i < 6; i++){ ma.wsrc[i] = wsrcs[i]; ma.wdst[i] = wdsts[i]; ma.wM[i] = Ms[i]; }
    ma.x = x; ma.xc = xc; ma.n4 = N*32;
    ma.cnt = (int*)acc; ma.nz4 = N*2;   // N*32 bytes in int4 granules
    ma.flag = flag;
  }
  int xB = (ma.n4 + 255) / 256;
  int zB = (ma.nz4 + 255) / 256;
  k_mega<<<1 + 320 + xB + zB, 256, 0, stream>>>(ma);

  // graph build + layer-0 GEMM fused: sharded u64 atomics overlap with MFMA
  const int Eb = (E + 255) / 256;
  const int rowBlocks = (N + 15) / 16;
  const int gB = (2*rowBlocks + 3) / 4;
  k_histgemm<<<gB + Eb, 256, 0, stream>>>(xc, WT0l, WT0r, bl0c, br0c, xlb16, xrb,
                                          N, rowBlocks, gB,
                                          ei, ew, acc, rank, E, N, flag);
  k_scan1<<<nB, 256, 0, stream>>>(acc, bsum, N);
  k_scan3<<<nB, 256, 0, stream>>>(acc, bsum, rowptr, pso, N, nB);
  k_scat_self<<<Eb + nB, 256, 0, stream>>>(ei, ew, rank, rowptr, acc, pso, csr,
                                           E, N, ET, flag, Eb);

  // layer 0 edge (gemm0 already done in k_histgemm)
  k_edge128<<<(N+3)/4, 256, 0, stream>>>(xlb16, xrb, rowptr, csr, We0c, at0c, bi0c, hb, N, ET);

  // layer 1
  k_gemm2<128><<<dim3(rowBlocks, 2), 64, 0, stream>>>(hb, WT1l, WT1r, bl1c, br1c, xlb16, xrb, N);
  k_edge128<<<(N+3)/4, 256, 0, stream>>>(xlb16, xrb, rowptr, csr, We1c, at1c, bi1c, hb, N, ET);

  // layer 2
  k_gemm2<64><<<dim3(rowBlocks, 2), 64, 0, stream>>>(hb, WT2l, WT2r, bl2c, br2c, xlb16, xrb, N);
  k_edge64<<<(N+3)/4, 256, 0, stream>>>(xlb16, xrb, rowptr, csr, We2c, at2c, bi2c,
                                        d_out, N, ET, flag);
}